// Round 20
// baseline (316.849 us; speedup 1.0000x reference)
//
#include <hip/hip_runtime.h>
#include <hip/hip_bf16.h>

#define S_LEN 2048
#define HIDDEN 4096
#define NH 32
#define NKV 8
#define HD 128
#define NQKV 6144   // NH*HD + 2*NKV*HD

typedef __bf16 bf16_t;
typedef __bf16 bf16x8 __attribute__((ext_vector_type(8)));
typedef __bf16 bf16x4 __attribute__((ext_vector_type(4)));
typedef float f32x4 __attribute__((ext_vector_type(4)));

typedef __attribute__((address_space(1))) void gvoid;
typedef __attribute__((address_space(3))) void lvoid;

__device__ __forceinline__ void gload_lds16(const void* g, void* l) {
    __builtin_amdgcn_global_load_lds((gvoid*)g, (lvoid*)l, 16, 0, 0);
}

__device__ __forceinline__ float fast_exp2(float x) {
    return __builtin_amdgcn_exp2f(x);   // v_exp_f32 (2^x native)
}

__device__ __forceinline__ unsigned int pack2_bf16(float lo, float hi) {
    bf16_t l = (bf16_t)lo, h = (bf16_t)hi;
    unsigned short lu, hu;
    __builtin_memcpy(&lu, &l, 2);
    __builtin_memcpy(&hu, &h, 2);
    return ((unsigned int)hu << 16) | (unsigned int)lu;
}

// ---------------- fused prep: 4 weight transpose-casts + hidden cast, ONE launch ----------------
__global__ __launch_bounds__(256) void prep_kernel(const float* __restrict__ hs,
                                                   const float* __restrict__ Wq,
                                                   const float* __restrict__ Wk,
                                                   const float* __restrict__ Wv,
                                                   const float* __restrict__ Wo,
                                                   bf16_t* __restrict__ hB,
                                                   bf16_t* __restrict__ WqkvT,
                                                   bf16_t* __restrict__ WoT) {
    __shared__ unsigned int t2[64][34];
    int b = blockIdx.x;
    const int t = threadIdx.x;
    if (b >= 10240) {   // hidden cast: 2048 blocks x 1024 float4
        int base = (b - 10240) * 1024 + t;
#pragma unroll
        for (int i = 0; i < 4; ++i) {
            int idx = base + i * 256;
            float4 v = ((const float4*)hs)[idx];
            bf16x4 o;
            o.x = (bf16_t)v.x; o.y = (bf16_t)v.y; o.z = (bf16_t)v.z; o.w = (bf16_t)v.w;
            ((bf16x4*)hB)[idx] = o;
        }
        return;
    }
    const float* in;
    bf16_t* out;
    int ldin, ldout, cx, ry;
    if (b < 4096) {
        in = Wq; out = WqkvT; ldin = HIDDEN; ldout = HIDDEN;
        cx = b & 63; ry = b >> 6;
    } else if (b < 5120) {
        b -= 4096;
        in = Wk; out = WqkvT + (size_t)4096 * HIDDEN; ldin = 1024; ldout = HIDDEN;
        cx = b & 15; ry = b >> 4;
    } else if (b < 6144) {
        b -= 5120;
        in = Wv; out = WqkvT + (size_t)5120 * HIDDEN; ldin = 1024; ldout = HIDDEN;
        cx = b & 15; ry = b >> 4;
    } else {
        b -= 6144;
        in = Wo; out = WoT; ldin = HIDDEN; ldout = HIDDEN;
        cx = b & 63; ry = b >> 6;
    }
    const int c0 = cx * 64, r0 = ry * 64;
    const int tx4 = t & 15, tp = t >> 4;
#pragma unroll
    for (int i = 0; i < 2; ++i) {
        int rp = tp + i * 16;
        const float* p0 = &in[(size_t)(r0 + 2 * rp) * ldin + c0 + tx4 * 4];
        float4 a = *(const float4*)p0;
        float4 bb = *(const float4*)(p0 + ldin);
        t2[tx4 * 4 + 0][rp] = pack2_bf16(a.x, bb.x);
        t2[tx4 * 4 + 1][rp] = pack2_bf16(a.y, bb.y);
        t2[tx4 * 4 + 2][rp] = pack2_bf16(a.z, bb.z);
        t2[tx4 * 4 + 3][rp] = pack2_bf16(a.w, bb.w);
    }
    __syncthreads();
    const int q = t & 3, cc = t >> 2;
    uint2 v0 = *(const uint2*)&t2[cc][q * 8 + 0];
    uint2 v1 = *(const uint2*)&t2[cc][q * 8 + 2];
    uint2 v2 = *(const uint2*)&t2[cc][q * 8 + 4];
    uint2 v3 = *(const uint2*)&t2[cc][q * 8 + 6];
    bf16_t* o = &out[(size_t)(c0 + cc) * ldout + r0 + q * 16];
    *(uint4*)o = make_uint4(v0.x, v0.y, v1.x, v1.y);
    *(uint4*)(o + 8) = make_uint4(v2.x, v2.y, v3.x, v3.y);
}

// ---------------- deep-pipeline 4-phase GEMM (m201-style ledger): 256x256, BK=64 ----------------
// 8 waves 2M x 4N, per-wave out 128x64 (8m x 4n frags). LDS: A/B halves [2par][2half][128x64]
// (+16KB scratch) = 144KB -> 1 block/CU. Half staged 6-7 phases before first read:
// cursor order A0,B0,A1,B1 per tile; prologue stages 7 halves; 1 half staged per phase.
// Phases per tile t (par=t&1): P1 reads A0,B0 (12 ds_read), P2 reads A1 (8), P3 reads B1 (4),
// P4 no reads (regs a0,b1 held). Gate vmcnt(4) ONLY at P4: at that point B1(t+1) is
// 3rd-newest staged half -> guaranteed landed; all t+1 halves covered. Stage-overwrite
// race-free: each buffer's overwrite is >=2 barriers after its last read, and a wave's
// reads complete before it passes the next barrier (consumed by its own MFMAs).
// Tail: cursor tiles >= NT redirect to scratch (uniform vmcnt ledger, never read).
template<typename OutT>
__global__ __launch_bounds__(512) void gemm_deep_kernel(const bf16_t* __restrict__ A,
                                                        const bf16_t* __restrict__ Bt,
                                                        OutT* __restrict__ C,
                                                        int M, int N, int K) {
    __shared__ bf16_t As[2][2][128 * 64];
    __shared__ bf16_t Bs[2][2][128 * 64];
    __shared__ bf16_t Sc[128 * 64];
    const int tid = threadIdx.x;
    const int lane = tid & 63, w = tid >> 6;
    const int wm = w >> 2, wn = w & 3;
    const int g = lane >> 4, c16 = lane & 15;
    const int c7 = c16 & 7;

    // XCD swizzle, bm-fastest (grid % 8 == 0)
    const int nbm = M / 256;
    const int cpx = gridDim.x >> 3;
    const int swz = (blockIdx.x & 7) * cpx + (blockIdx.x >> 3);
    const int bm = swz % nbm, bn = swz / nbm;

    const bf16_t* Abase = A + (size_t)(bm * 256) * K;
    const bf16_t* Bbase = Bt + (size_t)(bn * 256) * K;
    const int NT = K / 64;

    // stage one half (2 gloads/thread). cursor: tile=cur>>2, type=cur&3 (0:A0 1:B0 2:A1 3:B1)
    auto stageHalf = [&](int cur) {
        int tile = cur >> 2, type = cur & 3;
        bool dummy = (tile >= NT);
        int kt = dummy ? 0 : tile;
        int par = tile & 1;
        int h = type >> 1;
        if ((type & 1) == 0) {   // A half
            bf16_t* dst = dummy ? Sc : As[par][h];
#pragma unroll
            for (int j = 0; j < 2; ++j) {
                int idx = j * 512 + tid;
                int r = idx >> 3;
                int grow = (r & 63) + ((r >> 6) << 7) + h * 64;
                int gcol = kt * 64 + (((idx & 7) ^ (r & 7)) << 3);
                gload_lds16(Abase + (size_t)grow * K + gcol, dst + (size_t)(j * 512 + (w << 6)) * 8);
            }
        } else {                 // B half
            bf16_t* dst = dummy ? Sc : Bs[par][h];
#pragma unroll
            for (int j = 0; j < 2; ++j) {
                int idx = j * 512 + tid;
                int r = idx >> 3;
                int grow = ((r >> 5) << 6) + h * 32 + (r & 31);
                int gcol = kt * 64 + (((idx & 7) ^ (r & 7)) << 3);
                gload_lds16(Bbase + (size_t)grow * K + gcol, dst + (size_t)(j * 512 + (w << 6)) * 8);
            }
        }
    };
    auto rdA = [&](int par, int h, bf16x8 (&a)[2][4]) {
        const bf16_t* base = &As[par][h][0];
#pragma unroll
        for (int kk = 0; kk < 2; ++kk)
#pragma unroll
            for (int mi = 0; mi < 4; ++mi) {
                int r = wm * 64 + mi * 16 + c16;
                a[kk][mi] = *(const bf16x8*)&base[r * 64 + (((kk * 4 + g) ^ c7) << 3)];
            }
    };
    auto rdB = [&](int par, int h, bf16x8 (&b)[2][2]) {
        const bf16_t* base = &Bs[par][h][0];
#pragma unroll
        for (int kk = 0; kk < 2; ++kk)
#pragma unroll
            for (int nn = 0; nn < 2; ++nn) {
                int r = wn * 32 + nn * 16 + c16;
                b[kk][nn] = *(const bf16x8*)&base[r * 64 + (((kk * 4 + g) ^ c7) << 3)];
            }
    };

    f32x4 acc00[4][2], acc10[4][2], acc11[4][2], acc01[4][2];
#pragma unroll
    for (int mi = 0; mi < 4; ++mi)
#pragma unroll
        for (int nn = 0; nn < 2; ++nn) {
            acc00[mi][nn] = (f32x4){0.f, 0.f, 0.f, 0.f};
            acc10[mi][nn] = (f32x4){0.f, 0.f, 0.f, 0.f};
            acc11[mi][nn] = (f32x4){0.f, 0.f, 0.f, 0.f};
            acc01[mi][nn] = (f32x4){0.f, 0.f, 0.f, 0.f};
        }
    auto MM = [&](bf16x8 (&a)[2][4], bf16x8 (&b)[2][2], f32x4 (&acc)[4][2]) {
#pragma unroll
        for (int kk = 0; kk < 2; ++kk)
#pragma unroll
            for (int mi = 0; mi < 4; ++mi)
#pragma unroll
                for (int nn = 0; nn < 2; ++nn)
                    acc[mi][nn] = __builtin_amdgcn_mfma_f32_16x16x32_bf16(a[kk][mi], b[kk][nn], acc[mi][nn], 0, 0, 0);
    };

    // prologue: 7 halves (t0 complete + t1 A0,B0,A1); gate until t0 fully landed
    for (int c = 0; c < 7; ++c) stageHalf(c);
    asm volatile("s_waitcnt vmcnt(6)" ::: "memory");
    __builtin_amdgcn_s_barrier();
    __builtin_amdgcn_sched_barrier(0);

    int cur = 7;
    bf16x8 a0[2][4], a1[2][4], b0[2][2], b1[2][2];
    for (int t = 0; t < NT; ++t) {
        const int par = t & 1;
        // P1: quadrant (mh0, nh0); reads A0,B0
        __builtin_amdgcn_s_setprio(1);
        rdA(par, 0, a0); rdB(par, 0, b0);
        stageHalf(cur++);
        MM(a0, b0, acc00);
        __builtin_amdgcn_s_setprio(0);
        __builtin_amdgcn_s_barrier();
        __builtin_amdgcn_sched_barrier(0);
        // P2: (mh1, nh0); reads A1
        __builtin_amdgcn_s_setprio(1);
        rdA(par, 1, a1);
        stageHalf(cur++);
        MM(a1, b0, acc10);
        __builtin_amdgcn_s_setprio(0);
        __builtin_amdgcn_s_barrier();
        __builtin_amdgcn_sched_barrier(0);
        // P3: (mh1, nh1); reads B1
        __builtin_amdgcn_s_setprio(1);
        rdB(par, 1, b1);
        stageHalf(cur++);
        MM(a1, b1, acc11);
        __builtin_amdgcn_s_setprio(0);
        __builtin_amdgcn_s_barrier();
        __builtin_amdgcn_sched_barrier(0);
        // P4: (mh0, nh1); no reads (a0, b1 in regs). Gate: all t+1 halves landed.
        asm volatile("s_waitcnt vmcnt(4)" ::: "memory");
        __builtin_amdgcn_s_setprio(1);
        stageHalf(cur++);
        MM(a0, b1, acc01);
        __builtin_amdgcn_s_setprio(0);
        __builtin_amdgcn_s_barrier();
        __builtin_amdgcn_sched_barrier(0);
    }

    auto wr = [&](f32x4 (&acc)[4][2], int mh, int nh) {
#pragma unroll
        for (int mi = 0; mi < 4; ++mi)
#pragma unroll
            for (int nn = 0; nn < 2; ++nn) {
                int col = bn * 256 + wn * 64 + nh * 32 + nn * 16 + c16;
#pragma unroll
                for (int r = 0; r < 4; ++r) {
                    int row = bm * 256 + wm * 128 + mh * 64 + mi * 16 + g * 4 + r;
                    C[(size_t)row * N + col] = (OutT)acc[mi][nn][r];
                }
            }
    };
    wr(acc00, 0, 0); wr(acc10, 1, 0); wr(acc11, 1, 1); wr(acc01, 0, 1);
}

// ---------------- ring-3 counted-vmcnt GEMM (round-16 best; used for Wo, BN=128) ----------------
template<int BN, typename OutT>
__global__ __launch_bounds__(512, 2) void gemm_ring2_kernel(const bf16_t* __restrict__ A,
                                                            const bf16_t* __restrict__ Bt,
                                                            OutT* __restrict__ C,
                                                            int M, int N, int K) {
    constexpr int NF = BN / 32;
    __shared__ bf16_t As[3][256 * 32];
    __shared__ bf16_t Bs[3][BN * 32];
    const int tid = threadIdx.x;
    const int lane = tid & 63, w = tid >> 6;
    const int wm = w >> 1, wn = w & 1;
    const int g = lane >> 4, c16 = lane & 15;
    const int srow = lane >> 2;
    const int scg = ((lane & 3) ^ ((lane >> 3) & 3)) * 8;
    const int rdc = (g ^ ((c16 >> 1) & 3)) * 8;

    const int nbm = M / 256;
    const int cpx = gridDim.x >> 3;
    const int bid = blockIdx.x;
    const int swz = (bid & 7) * cpx + (bid >> 3);
    const int bm = swz % nbm, bn = swz / nbm;

    const bf16_t* Ab = A + (size_t)(bm * 256) * K;
    const bf16_t* Bb = Bt + (size_t)bn * BN * K;

    auto stage = [&](int slot, int kt) {
        const bf16_t* Ak = Ab + (size_t)kt * 32;
        const bf16_t* Bk = Bb + (size_t)kt * 32;
#pragma unroll
        for (int j = 0; j < 2; ++j) {
            int rb = 32 * w + 16 * j;
            gload_lds16(Ak + (size_t)(rb + srow) * K + scg, &As[slot][rb * 32]);
        }
        if constexpr (BN == 192) {
            if (w < 4) {
#pragma unroll
                for (int j = 0; j < 2; ++j) {
                    int rb = 32 * w + 16 * j;
                    gload_lds16(Bk + (size_t)(rb + srow) * K + scg, &Bs[slot][rb * 32]);
                }
            } else {
                int rb = 128 + 16 * (w - 4);
                gload_lds16(Bk + (size_t)(rb + srow) * K + scg, &Bs[slot][rb * 32]);
            }
        } else {
            int rb = 16 * w;
            gload_lds16(Bk + (size_t)(rb + srow) * K + scg, &Bs[slot][rb * 32]);
        }
    };

    f32x4 acc[4][NF];
#pragma unroll
    for (int i = 0; i < 4; ++i)
#pragma unroll
        for (int j = 0; j < NF; ++j)
            acc[i][j] = (f32x4){0.f, 0.f, 0.f, 0.f};

    const int NT = K / 32;
    stage(0, 0);
    stage(1, 1);

    int slot = 0, slot2 = 2;
    for (int t = 0; t < NT; ++t) {
        asm volatile("s_waitcnt vmcnt(3)" ::: "memory");
        __builtin_amdgcn_s_barrier();
        __builtin_amdgcn_sched_barrier(0);
        __builtin_amdgcn_s_setprio(1);

        bf16x8 af[4], bf[NF];
#pragma unroll
        for (int i = 0; i < 4; ++i) {
            int arow = wm * 64 + i * 16 + c16;
            af[i] = *(const bf16x8*)&As[slot][arow * 32 + rdc];
        }
#pragma unroll
        for (int j = 0; j < NF; ++j) {
            int brow = wn * (BN / 2) + j * 16 + c16;
            bf[j] = *(const bf16x8*)&Bs[slot][brow * 32 + rdc];
        }
        int nk = t + 2;
        if (nk >= NT) nk -= NT;
        stage(slot2, nk);

#pragma unroll
        for (int i = 0; i < 4; ++i)
#pragma unroll
            for (int j = 0; j < NF; ++j)
                acc[i][j] = __builtin_amdgcn_mfma_f32_16x16x32_bf16(af[i], bf[j], acc[i][j], 0, 0, 0);
        __builtin_amdgcn_s_setprio(0);

        slot = (slot + 1) % 3;
        slot2 = (slot2 + 1) % 3;
    }

#pragma unroll
    for (int mi = 0; mi < 4; ++mi)
#pragma unroll
        for (int ni = 0; ni < NF; ++ni) {
            int col = bn * BN + wn * (BN / 2) + ni * 16 + c16;
#pragma unroll
            for (int r = 0; r < 4; ++r) {
                int row = bm * 256 + wm * 64 + mi * 16 + g * 4 + r;
                C[(size_t)row * N + col] = (OutT)acc[mi][ni][r];
            }
        }
}

// ---------------- fused RoPE + V-transpose, ONE launch ----------------
__global__ __launch_bounds__(256) void rope_vt_kernel(const bf16_t* __restrict__ qkv,
                                                      bf16_t* __restrict__ Qr,
                                                      bf16_t* __restrict__ Kr,
                                                      bf16_t* __restrict__ Vt,
                                                      const int* __restrict__ pos) {
    const int t = threadIdx.x;
    int b = blockIdx.x;
    if (b < 512) {
        __shared__ unsigned int t2[64][34];
        const int cx = b & 15, ry = b >> 4;
        const int c0 = cx * 64, r0 = ry * 64;
        const bf16_t* in = qkv + 5120;
        const int tx4 = t & 15, tp = t >> 4;
#pragma unroll
        for (int i = 0; i < 2; ++i) {
            int rp = tp + i * 16;
            const bf16_t* p0 = &in[(size_t)(r0 + 2 * rp) * NQKV + c0 + tx4 * 4];
            bf16x4 a = *(const bf16x4*)p0;
            bf16x4 bb = *(const bf16x4*)(p0 + NQKV);
#pragma unroll
            for (int k2 = 0; k2 < 4; ++k2) {
                unsigned short lu, hu;
                bf16_t la = a[k2], hb = bb[k2];
                __builtin_memcpy(&lu, &la, 2);
                __builtin_memcpy(&hu, &hb, 2);
                t2[tx4 * 4 + k2][rp] = ((unsigned int)hu << 16) | (unsigned int)lu;
            }
        }
        __syncthreads();
        const int q = t & 3, cc = t >> 2;
        uint2 v0 = *(const uint2*)&t2[cc][q * 8 + 0];
        uint2 v1 = *(const uint2*)&t2[cc][q * 8 + 2];
        uint2 v2 = *(const uint2*)&t2[cc][q * 8 + 4];
        uint2 v3 = *(const uint2*)&t2[cc][q * 8 + 6];
        bf16_t* o = &Vt[(size_t)(c0 + cc) * S_LEN + r0 + q * 16];
        *(uint4*)o = make_uint4(v0.x, v0.y, v1.x, v1.y);
        *(uint4*)(o + 8) = make_uint4(v2.x, v2.y, v3.x, v3.y);
        return;
    }
    int idx = (b - 512) * 256 + t;
    int total = S_LEN * 40 * 64;
    if (idx >= total) return;
    int d = idx & 63;
    int h = (idx >> 6) % 40;
    int s = idx / (64 * 40);
    int colbase = (h < 32) ? h * 128 : 4096 + (h - 32) * 128;
    bf16_t* ob = (h < 32) ? Qr + ((size_t)h * S_LEN + s) * HD
                          : Kr + ((size_t)(h - 32) * S_LEN + s) * HD;
    float scale = (h < 32) ? 0.1275174310f : 1.0f;
    const bf16_t* base = qkv + (size_t)s * NQKV + colbase;
    float x0 = (float)base[d], x1 = (float)base[d + 64];
    float p = (float)pos[s];
    float invf = fast_exp2(-0.20762050593046935f * (float)d);
    float f = p * invf;
    float sn, cs;
    __sincosf(f, &sn, &cs);
    float o0 = (x0 * cs - x1 * sn) * scale;
    float o1 = (x1 * cs + x0 * sn) * scale;
    ob[d] = (bf16_t)o0;
    ob[d + 64] = (bf16_t)o1;
}

// ---------------- flash attention v5 (unchanged) ----------------
#define PLD 68
__global__ __launch_bounds__(512) void attn_kernel(const bf16_t* __restrict__ Q,
                                                   const bf16_t* __restrict__ K,
                                                   const bf16_t* __restrict__ Vt,
                                                   bf16_t* __restrict__ O) {
    __shared__ bf16_t Ks[4][64 * 128];
    __shared__ bf16_t Vs[4][128 * 64];
    __shared__ bf16_t Pl[8][16 * PLD];
    const int tid = threadIdx.x;
    const int lane = tid & 63, w = tid >> 6;
    const int bid = blockIdx.x;
    const int h = bid & 31;
    const int x = bid >> 5;
    const int grp = w >> 2, wi = w & 3;
    const int kv = h >> 2;
    const int quad = lane >> 4, c16 = lane & 15;
    const int c7 = c16 & 7;
    const bf16_t* Qh = Q + (size_t)h * S_LEN * HD;
    const bf16_t* Kh = K + (size_t)kv * S_LEN * HD;
    const bf16_t* Vh = Vt + (size_t)kv * HD * S_LEN;
    bf16_t* P = Pl[w];

    auto stage = [&](int slot, int kb) {
        bf16_t* Kd = Ks[slot];
        bf16_t* Vd = Vs[slot];
#pragma unroll
        for (int j = 0; j < 2; ++j) {
            int i = w * 2 + j;
            {
                int row = 4 * i + (lane >> 4);
                int sc = (lane & 15) ^ (row & 7);
                gload_lds16(Kh + (size_t)(kb + row) * HD + sc * 8, Kd + i * 512);
            }
            {
                int row = 8 * i + (lane >> 3);
                int sc = (lane & 7) ^ ((lane >> 3) & 7);
                gload_lds16(Vh + (size_t)row * S_LEN + kb + sc * 8, Vd + i * 512);
            }
        }
    };

    bf16x8 ones;
#pragma unroll
    for (int j = 0; j < 8; ++j) ones[j] = (bf16_t)1.0f;

    for (int ph = 0; ph < 2; ++ph) {
        const int qt = (ph == 0) ? x : 15 - x;
        const int R = qt + 1;
        const int qb = qt * 128 + wi * 32;

        bf16x8 qf[2][4];
#pragma unroll
        for (int rg = 0; rg < 2; ++rg)
#pragma unroll
            for (int c = 0; c < 4; ++c)
                qf[rg][c] = *(const bf16x8*)(Qh + (size_t)(qb + rg * 16 + c16) * HD + c * 32 + quad * 8);

        f32x4 acc_o[2][8];
#pragma unroll
        for (int rg = 0; rg < 2; ++rg)
#pragma unroll
            for (int dt = 0; dt < 8; ++dt) acc_o[rg][dt] = (f32x4){0.f, 0.f, 0.f, 0.f};
        f32x4 acc_l[2] = {(f32x4){0.f, 0.f, 0.f, 0.f}, (f32x4){0.f, 0.f, 0.f, 0.f}};
        float m[2][4];
#pragma unroll
        for (int rg = 0; rg < 2; ++rg)
#pragma unroll
            for (int r = 0; r < 4; ++r) m[rg][r] = -1e30f;

        stage(0, 0);
        stage(1, 64);
        __syncthreads();

        for (int r = 0; r < R; ++r) {
            int jn0 = 2 * r + 2, jn1 = 2 * r + 3;
            if (jn0 < 2 * R) stage(jn0 & 3, jn0 * 64);
            if (jn1 < 2 * R) stage(jn1 & 3, jn1 * 64);

            const int j = 2 * r + grp;
            const int kb = j * 64;
            const bf16_t* Kb = Ks[j & 3];
            const bf16_t* Vb = Vs[j & 3];

            if (kb <= qb + 31) {
                const bool diag = (kb + 63 > qb);

                f32x4 sacc[2][4];
#pragma unroll
                for (int rg = 0; rg < 2; ++rg)
#pragma unroll
                    for (int t = 0; t < 4; ++t) sacc[rg][t] = (f32x4){0.f, 0.f, 0.f, 0.f};
#pragma unroll
                for (int t = 0; t < 4; ++t) {
                    const bf16_t* krow = Kb + (t * 16 + c16) * 128;
#pragma unroll
                    for (int cc = 0; cc < 4; ++cc) {
                        bf16x8 kf = *(const bf16x8*)(krow + (((cc * 4 + quad) ^ c7) * 8));
                        sacc[0][t] = __builtin_amdgcn_mfma_f32_16x16x32_bf16(qf[0][cc], kf, sacc[0][t], 0, 0, 0);
                        sacc[1][t] = __builtin_amdgcn_mfma_f32_16x16x32_bf16(qf[1][cc], kf, sacc[1][t], 0, 0, 0);
                    }
                }
                bf16x8 pf[2][2];
#pragma unroll
                for (int rg = 0; rg < 2; ++rg) {
                    float p[4][4], mxr[4];
#pragma unroll
                    for (int r4 = 0; r4 < 4; ++r4) {
                        int qq = qb + rg * 16 + quad * 4 + r4;
#pragma unroll
                        for (int t = 0; t < 4; ++t) {
                            float sv = sacc[rg][t][r4];
                            if (diag && (kb + t * 16 + c16 > qq)) sv = -1e30f;
                            p[t][r4] = sv;
                        }
                        float mx = fmaxf(fmaxf(p[0][r4], p[1][r4]), fmaxf(p[2][r4], p[3][r4]));
                        mx = fmaxf(mx, __shfl_xor(mx, 1));
                        mx = fmaxf(mx, __shfl_xor(mx, 2));
                        mx = fmaxf(mx, __shfl_xor(mx, 4));
                        mx = fmaxf(mx, __shfl_xor(mx, 8));
                        mxr[r4] = mx;
                    }
                    bool resc = false;
#pragma unroll
                    for (int r4 = 0; r4 < 4; ++r4) resc = resc || (mxr[r4] > m[rg][r4] + 8.f);
                    if (__any(resc)) {
#pragma unroll
                        for (int r4 = 0; r4 < 4; ++r4) {
                            float mn = fmaxf(m[rg][r4], mxr[r4]);
                            float al = fast_exp2(m[rg][r4] - mn);
                            m[rg][r4] = mn;
                            acc_l[rg][r4] *= al;
#pragma unroll
                            for (int dt = 0; dt < 8; ++dt) acc_o[rg][dt][r4] *= al;
                        }
                    }
#pragma unroll
                    for (int r4 = 0; r4 < 4; ++r4)
#pragma unroll
                        for (int t = 0; t < 4; ++t)
                            p[t][r4] = fast_exp2(p[t][r4] - m[rg][r4]);
#pragma unroll
                    for (int t = 0; t < 4; ++t)
#pragma unroll
                        for (int r4 = 0; r4 < 4; ++r4)
                            P[(quad * 4 + r4) * PLD + t * 16 + c16] = (bf16_t)p[t][r4];
                    pf[rg][0] = *(const bf16x8*)(P + c16 * PLD + quad * 8);
                    pf[rg][1] = *(const bf16x8*)(P + c16 * PLD + 32 + quad * 8);
                }
                acc_l[0] = __builtin_amdgcn_mfma_f32_16x16x32_bf16(pf[0][0], ones, acc_l[0], 0, 0, 0);
                acc_l[0] = __builtin_amdgcn_mfma_f32_16x16x32_bf16(pf[0][1], ones, acc_l[0], 0, 0, 0);
                acc_l[1] = __builtin_amdgcn_mfma_f32_16x16x32_bf16(pf[1][0], ones, acc_l[1], 0, 0, 0);
                acc_l[1] = __builtin_amdgcn_mfma_f32_16x16x32_bf16(pf[1][1], ones, acc_l[1], 0, 0, 0);
#pragma unroll
                for (int dt = 0; dt < 8; ++dt) {
                    const bf16_t* vrow = Vb + (dt * 16 + c16) * 64;
                    bf16x8 vf0 = *(const bf16x8*)(vrow + ((quad ^ c7) * 8));
                    bf16x8 vf1 = *(const bf16x8*)(vrow + (((4 + quad) ^ c7) * 8));
                    acc_o[0][dt] = __builtin_amdgcn_mfma_f32_16x16x32_bf16(pf[0][0], vf0, acc_o[0][dt], 0, 0, 0);
                    acc_o[0][dt] = __builtin_amdgcn_mfma_f32_16x16x32_bf16(pf[0][1], vf1, acc_o[0][dt], 0, 0, 0);
                    acc_o[1][dt] = __builtin_amdgcn_mfma_f32_16x16x32_bf16(pf[1][0], vf0, acc_o[1][dt], 0, 0, 0);
                    acc_o[1][dt] = __builtin_amdgcn_mfma_f32_16x16x32_bf16(pf[1][1], vf1, acc_o[1][dt], 0, 0, 0);
                }
            }
            __syncthreads();
        }

        float* s0 = (float*)&Ks[0][0];
        float* s1 = (float*)&Vs[0][0];
        const int sl = wi * 64 + lane;
        if (grp == 1) {
#pragma unroll
            for (int rg = 0; rg < 2; ++rg)
#pragma unroll
                for (int r4 = 0; r4 < 4; ++r4) {
                    s0[(rg * 4 + r4) * 256 + sl] = m[rg][r4];
                    s0[(8 + rg * 4 + r4) * 256 + sl] = acc_l[rg][r4];
                }
#pragma unroll
            for (int dt = 0; dt < 8; ++dt)
#pragma unroll
                for (int r4 = 0; r4 < 4; ++r4) {
                    s0[(16 + dt * 4 + r4) * 256 + sl] = acc_o[0][dt][r4];
                    s1[(dt * 4 + r4) * 256 + sl] = acc_o[1][dt][r4];
                }
        }
        __syncthreads();
        if (grp == 0) {
#pragma unroll
            for (int rg = 0; rg < 2; ++rg)
#pragma unroll
                for (int r4 = 0; r4 < 4; ++r4) {
                    float m1 = s0[(rg * 4 + r4) * 256 + sl];
                    float l1 = s0[(8 + rg * 4 + r4) * 256 + sl];
                    float mm = fmaxf(m[rg][r4], m1);
                    float a0 = fast_exp2(m[rg][r4] - mm);
                    float a1 = fast_exp2(m1 - mm);
                    float ll = acc_l[rg][r4] * a0 + l1 * a1;
                    float inv = 1.f / ll;
                    bf16_t* orow = &O[(size_t)(qb + rg * 16 + quad * 4 + r4) * HIDDEN + h * HD];
#pragma unroll
                    for (int dt = 0; dt < 8; ++dt) {
                        float o1 = (rg == 0) ? s0[(16 + dt * 4 + r4) * 256 + sl]
                                             : s1[(dt * 4 + r4) * 256 + sl];
                        float val = (acc_o[rg][dt][r4] * a0 + o1 * a1) * inv;
                        orow[dt * 16 + c16] = (bf16_t)val;
                    }
                }
        }
        __syncthreads();
    }
}

// ---------------- host ----------------
extern "C" void kernel_launch(void* const* d_in, const int* in_sizes, int n_in,
                              void* d_out, int out_size, void* d_ws, size_t ws_size,
                              hipStream_t stream) {
    const float* hs = (const float*)d_in[0];
    const float* Wq = (const float*)d_in[1];
    const float* Wk = (const float*)d_in[2];
    const float* Wv = (const float*)d_in[3];
    const float* Wo = (const float*)d_in[4];
    const int* pos = (const int*)d_in[6];
    float* out = (float*)d_out;

    char* ws = (char*)d_ws;
    size_t off = 0;
    auto alloc = [&](size_t bytes) -> void* {
        void* p = ws + off;
        off += (bytes + 255) & ~(size_t)255;
        return p;
    };
    bf16_t* hB    = (bf16_t*)alloc((size_t)S_LEN * HIDDEN * 2);
    bf16_t* WqkvT = (bf16_t*)alloc((size_t)NQKV * HIDDEN * 2);   // [6144][4096]
    bf16_t* WoT   = (bf16_t*)alloc((size_t)HIDDEN * HIDDEN * 2);
    bf16_t* QKV   = (bf16_t*)alloc((size_t)S_LEN * NQKV * 2);    // [2048][6144] bf16
    bf16_t* Qr    = (bf16_t*)alloc((size_t)NH * S_LEN * HD * 2);
    bf16_t* Kr    = (bf16_t*)alloc((size_t)NKV * S_LEN * HD * 2);
    bf16_t* Vt    = (bf16_t*)alloc((size_t)NKV * HD * S_LEN * 2);
    bf16_t* Oat   = (bf16_t*)alloc((size_t)S_LEN * HIDDEN * 2);

    // 1. fused prep: 4 weight transpose-casts + hidden cast (12288 blocks)
    prep_kernel<<<12288, 256, 0, stream>>>(hs, Wq, Wk, Wv, Wo, hB, WqkvT, WoT);
    // 2. QKV projection, deep-pipeline 256x256 (192 blocks)
    gemm_deep_kernel<bf16_t><<<(S_LEN / 256) * (NQKV / 256), 512, 0, stream>>>(hB, WqkvT, QKV, S_LEN, NQKV, HIDDEN);
    // 3. fused RoPE + V-transpose
    rope_vt_kernel<<<512 + (S_LEN * 40 * 64 + 255) / 256, 256, 0, stream>>>(QKV, Qr, Kr, Vt, pos);
    // 4. flash attention v5: 256 blocks, 1/CU
    attn_kernel<<<256, 512, 0, stream>>>(Qr, Kr, Vt, Oat);
    // 5. output projection (fp32 out); ring2 BN=128 -> 256 blocks = 1/CU
    gemm_ring2_kernel<128, float><<<(S_LEN / 256) * (HIDDEN / 128), 512, 0, stream>>>(Oat, WoT, out, S_LEN, HIDDEN, HIDDEN);
}

// Round 21
// 316.439 us; speedup vs baseline: 1.0013x; 1.0013x over previous
//
#include <hip/hip_runtime.h>
#include <hip/hip_bf16.h>

#define S_LEN 2048
#define HIDDEN 4096
#define NH 32
#define NKV 8
#define HD 128
#define NQKV 6144   // NH*HD + 2*NKV*HD

typedef __bf16 bf16_t;
typedef __bf16 bf16x8 __attribute__((ext_vector_type(8)));
typedef __bf16 bf16x4 __attribute__((ext_vector_type(4)));
typedef float f32x4 __attribute__((ext_vector_type(4)));

typedef __attribute__((address_space(1))) void gvoid;
typedef __attribute__((address_space(3))) void lvoid;

__device__ __forceinline__ void gload_lds16(const void* g, void* l) {
    __builtin_amdgcn_global_load_lds((gvoid*)g, (lvoid*)l, 16, 0, 0);
}

__device__ __forceinline__ float fast_exp2(float x) {
    return __builtin_amdgcn_exp2f(x);   // v_exp_f32 (2^x native)
}

__device__ __forceinline__ unsigned int pack2_bf16(float lo, float hi) {
    bf16_t l = (bf16_t)lo, h = (bf16_t)hi;
    unsigned short lu, hu;
    __builtin_memcpy(&lu, &l, 2);
    __builtin_memcpy(&hu, &h, 2);
    return ((unsigned int)hu << 16) | (unsigned int)lu;
}

// ---------------- fused prep: 4 weight transpose-casts + hidden cast, ONE launch ----------------
__global__ __launch_bounds__(256) void prep_kernel(const float* __restrict__ hs,
                                                   const float* __restrict__ Wq,
                                                   const float* __restrict__ Wk,
                                                   const float* __restrict__ Wv,
                                                   const float* __restrict__ Wo,
                                                   bf16_t* __restrict__ hB,
                                                   bf16_t* __restrict__ WqkvT,
                                                   bf16_t* __restrict__ WoT) {
    __shared__ unsigned int t2[64][34];
    int b = blockIdx.x;
    const int t = threadIdx.x;
    if (b >= 10240) {   // hidden cast: 2048 blocks x 1024 float4
        int base = (b - 10240) * 1024 + t;
#pragma unroll
        for (int i = 0; i < 4; ++i) {
            int idx = base + i * 256;
            float4 v = ((const float4*)hs)[idx];
            bf16x4 o;
            o.x = (bf16_t)v.x; o.y = (bf16_t)v.y; o.z = (bf16_t)v.z; o.w = (bf16_t)v.w;
            ((bf16x4*)hB)[idx] = o;
        }
        return;
    }
    const float* in;
    bf16_t* out;
    int ldin, ldout, cx, ry;
    if (b < 4096) {
        in = Wq; out = WqkvT; ldin = HIDDEN; ldout = HIDDEN;
        cx = b & 63; ry = b >> 6;
    } else if (b < 5120) {
        b -= 4096;
        in = Wk; out = WqkvT + (size_t)4096 * HIDDEN; ldin = 1024; ldout = HIDDEN;
        cx = b & 15; ry = b >> 4;
    } else if (b < 6144) {
        b -= 5120;
        in = Wv; out = WqkvT + (size_t)5120 * HIDDEN; ldin = 1024; ldout = HIDDEN;
        cx = b & 15; ry = b >> 4;
    } else {
        b -= 6144;
        in = Wo; out = WoT; ldin = HIDDEN; ldout = HIDDEN;
        cx = b & 63; ry = b >> 6;
    }
    const int c0 = cx * 64, r0 = ry * 64;
    const int tx4 = t & 15, tp = t >> 4;
#pragma unroll
    for (int i = 0; i < 2; ++i) {
        int rp = tp + i * 16;
        const float* p0 = &in[(size_t)(r0 + 2 * rp) * ldin + c0 + tx4 * 4];
        float4 a = *(const float4*)p0;
        float4 bb = *(const float4*)(p0 + ldin);
        t2[tx4 * 4 + 0][rp] = pack2_bf16(a.x, bb.x);
        t2[tx4 * 4 + 1][rp] = pack2_bf16(a.y, bb.y);
        t2[tx4 * 4 + 2][rp] = pack2_bf16(a.z, bb.z);
        t2[tx4 * 4 + 3][rp] = pack2_bf16(a.w, bb.w);
    }
    __syncthreads();
    const int q = t & 3, cc = t >> 2;
    uint2 v0 = *(const uint2*)&t2[cc][q * 8 + 0];
    uint2 v1 = *(const uint2*)&t2[cc][q * 8 + 2];
    uint2 v2 = *(const uint2*)&t2[cc][q * 8 + 4];
    uint2 v3 = *(const uint2*)&t2[cc][q * 8 + 6];
    bf16_t* o = &out[(size_t)(c0 + cc) * ldout + r0 + q * 16];
    *(uint4*)o = make_uint4(v0.x, v0.y, v1.x, v1.y);
    *(uint4*)(o + 8) = make_uint4(v2.x, v2.y, v3.x, v3.y);
}

// ---------------- ring-3 counted-vmcnt GEMM: BM=256, per-wave 64x(BN/2) (measured best) ----------------
template<int BN, typename OutT>
__global__ __launch_bounds__(512, 2) void gemm_ring2_kernel(const bf16_t* __restrict__ A,
                                                            const bf16_t* __restrict__ Bt,
                                                            OutT* __restrict__ C,
                                                            int M, int N, int K) {
    constexpr int NF = BN / 32;          // per-wave col frags (6 for 192, 4 for 128)
    __shared__ bf16_t As[3][256 * 32];
    __shared__ bf16_t Bs[3][BN * 32];
    const int tid = threadIdx.x;
    const int lane = tid & 63, w = tid >> 6;
    const int wm = w >> 1, wn = w & 1;
    const int g = lane >> 4, c16 = lane & 15;
    const int srow = lane >> 2;                              // row within a 16-row DMA instr
    const int scg = ((lane & 3) ^ ((lane >> 3) & 3)) * 8;    // pre-swizzled global chunk (elems)
    const int rdc = (g ^ ((c16 >> 1) & 3)) * 8;              // swizzled read chunk (elems)

    // XCD swizzle, bm-fastest
    const int nbm = M / 256;
    const int cpx = gridDim.x >> 3;
    const int bid = blockIdx.x;
    const int swz = (bid & 7) * cpx + (bid >> 3);
    const int bm = swz % nbm, bn = swz / nbm;

    const bf16_t* Ab = A + (size_t)(bm * 256) * K;
    const bf16_t* Bb = Bt + (size_t)bn * BN * K;

    auto stage = [&](int slot, int kt) {
        const bf16_t* Ak = Ab + (size_t)kt * 32;
        const bf16_t* Bk = Bb + (size_t)kt * 32;
#pragma unroll
        for (int j = 0; j < 2; ++j) {    // A: 16 instrs, 2/wave (rows 32w..32w+31)
            int rb = 32 * w + 16 * j;
            gload_lds16(Ak + (size_t)(rb + srow) * K + scg, &As[slot][rb * 32]);
        }
        if constexpr (BN == 192) {       // B: 12 instrs: waves 0-3 x2, waves 4-7 x1
            if (w < 4) {
#pragma unroll
                for (int j = 0; j < 2; ++j) {
                    int rb = 32 * w + 16 * j;
                    gload_lds16(Bk + (size_t)(rb + srow) * K + scg, &Bs[slot][rb * 32]);
                }
            } else {
                int rb = 128 + 16 * (w - 4);
                gload_lds16(Bk + (size_t)(rb + srow) * K + scg, &Bs[slot][rb * 32]);
            }
        } else {                         // BN==128: B 8 instrs, 1/wave
            int rb = 16 * w;
            gload_lds16(Bk + (size_t)(rb + srow) * K + scg, &Bs[slot][rb * 32]);
        }
    };

    f32x4 acc[4][NF];
#pragma unroll
    for (int i = 0; i < 4; ++i)
#pragma unroll
        for (int j = 0; j < NF; ++j)
            acc[i][j] = (f32x4){0.f, 0.f, 0.f, 0.f};

    const int NT = K / 32;
    stage(0, 0);
    stage(1, 1);

    int slot = 0, slot2 = 2;             // slot = t%3, slot2 = (t+2)%3
    for (int t = 0; t < NT; ++t) {
        asm volatile("s_waitcnt vmcnt(3)" ::: "memory");
        __builtin_amdgcn_s_barrier();
        __builtin_amdgcn_sched_barrier(0);
        __builtin_amdgcn_s_setprio(1);

        bf16x8 af[4], bf[NF];
#pragma unroll
        for (int i = 0; i < 4; ++i) {
            int arow = wm * 64 + i * 16 + c16;
            af[i] = *(const bf16x8*)&As[slot][arow * 32 + rdc];
        }
#pragma unroll
        for (int j = 0; j < NF; ++j) {
            int brow = wn * (BN / 2) + j * 16 + c16;
            bf[j] = *(const bf16x8*)&Bs[slot][brow * 32 + rdc];
        }
        int nk = t + 2;
        if (nk >= NT) nk -= NT;          // wrap-stage: keeps ledger uniform, never read
        stage(slot2, nk);

        // NO lgkmcnt(0) fence: compiler interleaves ds_reads with MFMAs (counted lgkmcnt)
#pragma unroll
        for (int i = 0; i < 4; ++i)
#pragma unroll
            for (int j = 0; j < NF; ++j)
                acc[i][j] = __builtin_amdgcn_mfma_f32_16x16x32_bf16(af[i], bf[j], acc[i][j], 0, 0, 0);
        __builtin_amdgcn_s_setprio(0);

        slot = (slot + 1) % 3;
        slot2 = (slot2 + 1) % 3;
    }

#pragma unroll
    for (int mi = 0; mi < 4; ++mi)
#pragma unroll
        for (int ni = 0; ni < NF; ++ni) {
            int col = bn * BN + wn * (BN / 2) + ni * 16 + c16;
#pragma unroll
            for (int r = 0; r < 4; ++r) {
                int row = bm * 256 + wm * 64 + mi * 16 + g * 4 + r;
                C[(size_t)row * N + col] = (OutT)acc[mi][ni][r];
            }
        }
}

// ---------------- fused RoPE + V-transpose, ONE launch ----------------
__global__ __launch_bounds__(256) void rope_vt_kernel(const bf16_t* __restrict__ qkv,
                                                      bf16_t* __restrict__ Qr,
                                                      bf16_t* __restrict__ Kr,
                                                      bf16_t* __restrict__ Vt,
                                                      const int* __restrict__ pos) {
    const int t = threadIdx.x;
    int b = blockIdx.x;
    if (b < 512) {
        __shared__ unsigned int t2[64][34];
        const int cx = b & 15, ry = b >> 4;
        const int c0 = cx * 64, r0 = ry * 64;
        const bf16_t* in = qkv + 5120;
        const int tx4 = t & 15, tp = t >> 4;
#pragma unroll
        for (int i = 0; i < 2; ++i) {
            int rp = tp + i * 16;
            const bf16_t* p0 = &in[(size_t)(r0 + 2 * rp) * NQKV + c0 + tx4 * 4];
            bf16x4 a = *(const bf16x4*)p0;
            bf16x4 bb = *(const bf16x4*)(p0 + NQKV);
#pragma unroll
            for (int k2 = 0; k2 < 4; ++k2) {
                unsigned short lu, hu;
                bf16_t la = a[k2], hb = bb[k2];
                __builtin_memcpy(&lu, &la, 2);
                __builtin_memcpy(&hu, &hb, 2);
                t2[tx4 * 4 + k2][rp] = ((unsigned int)hu << 16) | (unsigned int)lu;
            }
        }
        __syncthreads();
        const int q = t & 3, cc = t >> 2;
        uint2 v0 = *(const uint2*)&t2[cc][q * 8 + 0];
        uint2 v1 = *(const uint2*)&t2[cc][q * 8 + 2];
        uint2 v2 = *(const uint2*)&t2[cc][q * 8 + 4];
        uint2 v3 = *(const uint2*)&t2[cc][q * 8 + 6];
        bf16_t* o = &Vt[(size_t)(c0 + cc) * S_LEN + r0 + q * 16];
        *(uint4*)o = make_uint4(v0.x, v0.y, v1.x, v1.y);
        *(uint4*)(o + 8) = make_uint4(v2.x, v2.y, v3.x, v3.y);
        return;
    }
    int idx = (b - 512) * 256 + t;
    int total = S_LEN * 40 * 64;
    if (idx >= total) return;
    int d = idx & 63;
    int h = (idx >> 6) % 40;
    int s = idx / (64 * 40);
    int colbase = (h < 32) ? h * 128 : 4096 + (h - 32) * 128;
    bf16_t* ob = (h < 32) ? Qr + ((size_t)h * S_LEN + s) * HD
                          : Kr + ((size_t)(h - 32) * S_LEN + s) * HD;
    float scale = (h < 32) ? 0.1275174310f : 1.0f;
    const bf16_t* base = qkv + (size_t)s * NQKV + colbase;
    float x0 = (float)base[d], x1 = (float)base[d + 64];
    float p = (float)pos[s];
    float invf = fast_exp2(-0.20762050593046935f * (float)d);
    float f = p * invf;
    float sn, cs;
    __sincosf(f, &sn, &cs);
    float o0 = (x0 * cs - x1 * sn) * scale;
    float o1 = (x1 * cs + x0 * sn) * scale;
    ob[d] = (bf16_t)o0;
    ob[d + 64] = (bf16_t)o1;
}

// ---------------- flash attention v5 ----------------
#define PLD 68
__global__ __launch_bounds__(512) void attn_kernel(const bf16_t* __restrict__ Q,
                                                   const bf16_t* __restrict__ K,
                                                   const bf16_t* __restrict__ Vt,
                                                   bf16_t* __restrict__ O) {
    __shared__ bf16_t Ks[4][64 * 128];
    __shared__ bf16_t Vs[4][128 * 64];
    __shared__ bf16_t Pl[8][16 * PLD];
    const int tid = threadIdx.x;
    const int lane = tid & 63, w = tid >> 6;
    const int bid = blockIdx.x;
    const int h = bid & 31;
    const int x = bid >> 5;
    const int grp = w >> 2, wi = w & 3;
    const int kv = h >> 2;
    const int quad = lane >> 4, c16 = lane & 15;
    const int c7 = c16 & 7;
    const bf16_t* Qh = Q + (size_t)h * S_LEN * HD;
    const bf16_t* Kh = K + (size_t)kv * S_LEN * HD;
    const bf16_t* Vh = Vt + (size_t)kv * HD * S_LEN;
    bf16_t* P = Pl[w];

    auto stage = [&](int slot, int kb) {
        bf16_t* Kd = Ks[slot];
        bf16_t* Vd = Vs[slot];
#pragma unroll
        for (int j = 0; j < 2; ++j) {
            int i = w * 2 + j;
            {
                int row = 4 * i + (lane >> 4);
                int sc = (lane & 15) ^ (row & 7);
                gload_lds16(Kh + (size_t)(kb + row) * HD + sc * 8, Kd + i * 512);
            }
            {
                int row = 8 * i + (lane >> 3);
                int sc = (lane & 7) ^ ((lane >> 3) & 7);
                gload_lds16(Vh + (size_t)row * S_LEN + kb + sc * 8, Vd + i * 512);
            }
        }
    };

    bf16x8 ones;
#pragma unroll
    for (int j = 0; j < 8; ++j) ones[j] = (bf16_t)1.0f;

    for (int ph = 0; ph < 2; ++ph) {
        const int qt = (ph == 0) ? x : 15 - x;
        const int R = qt + 1;
        const int qb = qt * 128 + wi * 32;

        bf16x8 qf[2][4];
#pragma unroll
        for (int rg = 0; rg < 2; ++rg)
#pragma unroll
            for (int c = 0; c < 4; ++c)
                qf[rg][c] = *(const bf16x8*)(Qh + (size_t)(qb + rg * 16 + c16) * HD + c * 32 + quad * 8);

        f32x4 acc_o[2][8];
#pragma unroll
        for (int rg = 0; rg < 2; ++rg)
#pragma unroll
            for (int dt = 0; dt < 8; ++dt) acc_o[rg][dt] = (f32x4){0.f, 0.f, 0.f, 0.f};
        f32x4 acc_l[2] = {(f32x4){0.f, 0.f, 0.f, 0.f}, (f32x4){0.f, 0.f, 0.f, 0.f}};
        float m[2][4];
#pragma unroll
        for (int rg = 0; rg < 2; ++rg)
#pragma unroll
            for (int r = 0; r < 4; ++r) m[rg][r] = -1e30f;

        stage(0, 0);
        stage(1, 64);
        __syncthreads();

        for (int r = 0; r < R; ++r) {
            int jn0 = 2 * r + 2, jn1 = 2 * r + 3;
            if (jn0 < 2 * R) stage(jn0 & 3, jn0 * 64);
            if (jn1 < 2 * R) stage(jn1 & 3, jn1 * 64);

            const int j = 2 * r + grp;
            const int kb = j * 64;
            const bf16_t* Kb = Ks[j & 3];
            const bf16_t* Vb = Vs[j & 3];

            if (kb <= qb + 31) {
                const bool diag = (kb + 63 > qb);

                f32x4 sacc[2][4];
#pragma unroll
                for (int rg = 0; rg < 2; ++rg)
#pragma unroll
                    for (int t = 0; t < 4; ++t) sacc[rg][t] = (f32x4){0.f, 0.f, 0.f, 0.f};
#pragma unroll
                for (int t = 0; t < 4; ++t) {
                    const bf16_t* krow = Kb + (t * 16 + c16) * 128;
#pragma unroll
                    for (int cc = 0; cc < 4; ++cc) {
                        bf16x8 kf = *(const bf16x8*)(krow + (((cc * 4 + quad) ^ c7) * 8));
                        sacc[0][t] = __builtin_amdgcn_mfma_f32_16x16x32_bf16(qf[0][cc], kf, sacc[0][t], 0, 0, 0);
                        sacc[1][t] = __builtin_amdgcn_mfma_f32_16x16x32_bf16(qf[1][cc], kf, sacc[1][t], 0, 0, 0);
                    }
                }
                bf16x8 pf[2][2];
#pragma unroll
                for (int rg = 0; rg < 2; ++rg) {
                    float p[4][4], mxr[4];
#pragma unroll
                    for (int r4 = 0; r4 < 4; ++r4) {
                        int qq = qb + rg * 16 + quad * 4 + r4;
#pragma unroll
                        for (int t = 0; t < 4; ++t) {
                            float sv = sacc[rg][t][r4];
                            if (diag && (kb + t * 16 + c16 > qq)) sv = -1e30f;
                            p[t][r4] = sv;
                        }
                        float mx = fmaxf(fmaxf(p[0][r4], p[1][r4]), fmaxf(p[2][r4], p[3][r4]));
                        mx = fmaxf(mx, __shfl_xor(mx, 1));
                        mx = fmaxf(mx, __shfl_xor(mx, 2));
                        mx = fmaxf(mx, __shfl_xor(mx, 4));
                        mx = fmaxf(mx, __shfl_xor(mx, 8));
                        mxr[r4] = mx;
                    }
                    bool resc = false;
#pragma unroll
                    for (int r4 = 0; r4 < 4; ++r4) resc = resc || (mxr[r4] > m[rg][r4] + 8.f);
                    if (__any(resc)) {
#pragma unroll
                        for (int r4 = 0; r4 < 4; ++r4) {
                            float mn = fmaxf(m[rg][r4], mxr[r4]);
                            float al = fast_exp2(m[rg][r4] - mn);
                            m[rg][r4] = mn;
                            acc_l[rg][r4] *= al;
#pragma unroll
                            for (int dt = 0; dt < 8; ++dt) acc_o[rg][dt][r4] *= al;
                        }
                    }
#pragma unroll
                    for (int r4 = 0; r4 < 4; ++r4)
#pragma unroll
                        for (int t = 0; t < 4; ++t)
                            p[t][r4] = fast_exp2(p[t][r4] - m[rg][r4]);
#pragma unroll
                    for (int t = 0; t < 4; ++t)
#pragma unroll
                        for (int r4 = 0; r4 < 4; ++r4)
                            P[(quad * 4 + r4) * PLD + t * 16 + c16] = (bf16_t)p[t][r4];
                    pf[rg][0] = *(const bf16x8*)(P + c16 * PLD + quad * 8);
                    pf[rg][1] = *(const bf16x8*)(P + c16 * PLD + 32 + quad * 8);
                }
                acc_l[0] = __builtin_amdgcn_mfma_f32_16x16x32_bf16(pf[0][0], ones, acc_l[0], 0, 0, 0);
                acc_l[0] = __builtin_amdgcn_mfma_f32_16x16x32_bf16(pf[0][1], ones, acc_l[0], 0, 0, 0);
                acc_l[1] = __builtin_amdgcn_mfma_f32_16x16x32_bf16(pf[1][0], ones, acc_l[1], 0, 0, 0);
                acc_l[1] = __builtin_amdgcn_mfma_f32_16x16x32_bf16(pf[1][1], ones, acc_l[1], 0, 0, 0);
#pragma unroll
                for (int dt = 0; dt < 8; ++dt) {
                    const bf16_t* vrow = Vb + (dt * 16 + c16) * 64;
                    bf16x8 vf0 = *(const bf16x8*)(vrow + ((quad ^ c7) * 8));
                    bf16x8 vf1 = *(const bf16x8*)(vrow + (((4 + quad) ^ c7) * 8));
                    acc_o[0][dt] = __builtin_amdgcn_mfma_f32_16x16x32_bf16(pf[0][0], vf0, acc_o[0][dt], 0, 0, 0);
                    acc_o[0][dt] = __builtin_amdgcn_mfma_f32_16x16x32_bf16(pf[0][1], vf1, acc_o[0][dt], 0, 0, 0);
                    acc_o[1][dt] = __builtin_amdgcn_mfma_f32_16x16x32_bf16(pf[1][0], vf0, acc_o[1][dt], 0, 0, 0);
                    acc_o[1][dt] = __builtin_amdgcn_mfma_f32_16x16x32_bf16(pf[1][1], vf1, acc_o[1][dt], 0, 0, 0);
                }
            }
            __syncthreads();
        }

        float* s0 = (float*)&Ks[0][0];
        float* s1 = (float*)&Vs[0][0];
        const int sl = wi * 64 + lane;
        if (grp == 1) {
#pragma unroll
            for (int rg = 0; rg < 2; ++rg)
#pragma unroll
                for (int r4 = 0; r4 < 4; ++r4) {
                    s0[(rg * 4 + r4) * 256 + sl] = m[rg][r4];
                    s0[(8 + rg * 4 + r4) * 256 + sl] = acc_l[rg][r4];
                }
#pragma unroll
            for (int dt = 0; dt < 8; ++dt)
#pragma unroll
                for (int r4 = 0; r4 < 4; ++r4) {
                    s0[(16 + dt * 4 + r4) * 256 + sl] = acc_o[0][dt][r4];
                    s1[(dt * 4 + r4) * 256 + sl] = acc_o[1][dt][r4];
                }
        }
        __syncthreads();
        if (grp == 0) {
#pragma unroll
            for (int rg = 0; rg < 2; ++rg)
#pragma unroll
                for (int r4 = 0; r4 < 4; ++r4) {
                    float m1 = s0[(rg * 4 + r4) * 256 + sl];
                    float l1 = s0[(8 + rg * 4 + r4) * 256 + sl];
                    float mm = fmaxf(m[rg][r4], m1);
                    float a0 = fast_exp2(m[rg][r4] - mm);
                    float a1 = fast_exp2(m1 - mm);
                    float ll = acc_l[rg][r4] * a0 + l1 * a1;
                    float inv = 1.f / ll;
                    bf16_t* orow = &O[(size_t)(qb + rg * 16 + quad * 4 + r4) * HIDDEN + h * HD];
#pragma unroll
                    for (int dt = 0; dt < 8; ++dt) {
                        float o1 = (rg == 0) ? s0[(16 + dt * 4 + r4) * 256 + sl]
                                             : s1[(dt * 4 + r4) * 256 + sl];
                        float val = (acc_o[rg][dt][r4] * a0 + o1 * a1) * inv;
                        orow[dt * 16 + c16] = (bf16_t)val;
                    }
                }
        }
        __syncthreads();
    }
}

// ---------------- host ----------------
extern "C" void kernel_launch(void* const* d_in, const int* in_sizes, int n_in,
                              void* d_out, int out_size, void* d_ws, size_t ws_size,
                              hipStream_t stream) {
    const float* hs = (const float*)d_in[0];
    const float* Wq = (const float*)d_in[1];
    const float* Wk = (const float*)d_in[2];
    const float* Wv = (const float*)d_in[3];
    const float* Wo = (const float*)d_in[4];
    const int* pos = (const int*)d_in[6];
    float* out = (float*)d_out;

    char* ws = (char*)d_ws;
    size_t off = 0;
    auto alloc = [&](size_t bytes) -> void* {
        void* p = ws + off;
        off += (bytes + 255) & ~(size_t)255;
        return p;
    };
    bf16_t* hB    = (bf16_t*)alloc((size_t)S_LEN * HIDDEN * 2);
    bf16_t* WqkvT = (bf16_t*)alloc((size_t)NQKV * HIDDEN * 2);   // [6144][4096]
    bf16_t* WoT   = (bf16_t*)alloc((size_t)HIDDEN * HIDDEN * 2);
    bf16_t* QKV   = (bf16_t*)alloc((size_t)S_LEN * NQKV * 2);    // [2048][6144] bf16
    bf16_t* Qr    = (bf16_t*)alloc((size_t)NH * S_LEN * HD * 2);
    bf16_t* Kr    = (bf16_t*)alloc((size_t)NKV * S_LEN * HD * 2);
    bf16_t* Vt    = (bf16_t*)alloc((size_t)NKV * HD * S_LEN * 2);
    bf16_t* Oat   = (bf16_t*)alloc((size_t)S_LEN * HIDDEN * 2);

    // 1. fused prep: 4 weight transpose-casts + hidden cast (12288 blocks)
    prep_kernel<<<12288, 256, 0, stream>>>(hs, Wq, Wk, Wv, Wo, hB, WqkvT, WoT);
    // 2. fused QKV projection -> bf16 [2048][6144]; BN=192 -> 256 blocks = 1/CU
    gemm_ring2_kernel<192, bf16_t><<<(S_LEN / 256) * (NQKV / 192), 512, 0, stream>>>(hB, WqkvT, QKV, S_LEN, NQKV, HIDDEN);
    // 3. fused RoPE + V-transpose
    rope_vt_kernel<<<512 + (S_LEN * 40 * 64 + 255) / 256, 256, 0, stream>>>(QKV, Qr, Kr, Vt, pos);
    // 4. flash attention v5: 256 blocks, 1/CU
    attn_kernel<<<256, 512, 0, stream>>>(Qr, Kr, Vt, Oat);
    // 5. output projection (fp32 out); BN=128 -> 256 blocks = 1/CU
    gemm_ring2_kernel<128, float><<<(S_LEN / 256) * (HIDDEN / 128), 512, 0, stream>>>(Oat, WoT, out, S_LEN, HIDDEN, HIDDEN);
}